// Round 5
// baseline (773.381 us; speedup 1.0000x reference)
//
#include <hip/hip_runtime.h>
#include <hip/hip_bf16.h>

#define NN 20000      // nodes
#define NE 320000     // edges
#define NG 64         // graphs
#define HEADS 4
#define CD 32         // dim per head
#define HC 128        // HEADS*CD
#define ED 16         // edge feature dim

// ---- node GEMM: out = x @ W for one of {Wq,Wk,Wv} selected by blockIdx.y ----
// 32 nodes / 256-thread block; thread: tx=t&31 -> cols tx*4..+4, ty=t>>5 -> nodes ty*4..+4
__global__ __launch_bounds__(256) void k_qkv(const float* __restrict__ xin,
        const float* __restrict__ Wq, const float* __restrict__ Wk,
        const float* __restrict__ Wv,
        float* __restrict__ qo, float* __restrict__ ko, float* __restrict__ vo) {
    __shared__ float xs[32 * HC];   // 16 KB
    const int t = threadIdx.x;
    const int n0 = blockIdx.x * 32;
    const int sel = blockIdx.y;
    const float* __restrict__ W = (sel == 0) ? Wq : (sel == 1) ? Wk : Wv;
    float* __restrict__ outp = (sel == 0) ? qo : (sel == 1) ? ko : vo;
    {
        const float4* src = (const float4*)(xin + (size_t)n0 * HC);
        float4* dst = (float4*)xs;
        #pragma unroll
        for (int i = 0; i < 4; ++i)
            dst[t + 256 * i] = src[t + 256 * i];
    }
    __syncthreads();
    const int tx = t & 31, ty = t >> 5;
    const int c0 = tx * 4, m0 = ty * 4;
    float acc[4][4];
    #pragma unroll
    for (int im = 0; im < 4; ++im)
        #pragma unroll
        for (int c = 0; c < 4; ++c) acc[im][c] = 0.f;

    #pragma unroll 2
    for (int kk = 0; kk < HC; kk += 4) {
        float xfrag[4][4];
        #pragma unroll
        for (int im = 0; im < 4; ++im) {
            float4 xf = *(const float4*)&xs[(m0 + im) * HC + kk];
            xfrag[im][0] = xf.x; xfrag[im][1] = xf.y;
            xfrag[im][2] = xf.z; xfrag[im][3] = xf.w;
        }
        #pragma unroll
        for (int r = 0; r < 4; ++r) {
            float4 w = *(const float4*)&W[(size_t)(kk + r) * HC + c0];
            #pragma unroll
            for (int im = 0; im < 4; ++im) {
                float xv = xfrag[im][r];
                acc[im][0] += xv * w.x; acc[im][1] += xv * w.y;
                acc[im][2] += xv * w.z; acc[im][3] += xv * w.w;
            }
        }
    }
    #pragma unroll
    for (int im = 0; im < 4; ++im) {
        const size_t n = (size_t)(n0 + m0 + im);
        *(float4*)&outp[n * HC + c0] =
            make_float4(acc[im][0], acc[im][1], acc[im][2], acc[im][3]);
    }
}

// ---- CSR build ----
__global__ void k_hist(const int* __restrict__ ei, int* __restrict__ deg) {
    int i = blockIdx.x * blockDim.x + threadIdx.x;
    if (i < NE) atomicAdd(&deg[ei[NE + i]], 1);
}

__global__ __launch_bounds__(1024) void k_scan(const int* __restrict__ deg,
        int* __restrict__ rowptr, int* __restrict__ nextp) {
    __shared__ int part[1024];
    const int t = threadIdx.x;
    const int b0 = t * 20;
    const int b1 = min(b0 + 20, NN);
    int s = 0;
    for (int i = b0; i < b1; ++i) s += deg[i];
    part[t] = s;
    __syncthreads();
    for (int off = 1; off < 1024; off <<= 1) {
        int val = (t >= off) ? part[t - off] : 0;
        __syncthreads();
        part[t] += val;
        __syncthreads();
    }
    int run = (t == 0) ? 0 : part[t - 1];
    for (int i = b0; i < b1; ++i) {
        rowptr[i] = run;
        nextp[i] = run;
        run += deg[i];
    }
    if (b1 == NN) rowptr[NN] = run;
}

__global__ void k_scatter(const int* __restrict__ ei, int* __restrict__ nextp,
        int2* __restrict__ ecsr) {
    int i = blockIdx.x * blockDim.x + threadIdx.x;
    if (i < NE) {
        int d = ei[NE + i];
        int pos = atomicAdd(&nextp[d], 1);
        ecsr[pos] = make_int2(ei[i], i);   // (src, eid)
    }
}

__global__ void k_count(const int* __restrict__ batch, float* __restrict__ cnt) {
    int i = blockIdx.x * blockDim.x + threadIdx.x;
    if (i < NN) atomicAdd(&cnt[batch[i]], 1.f);
}

// ---- fused conv: one wave per dst node; 2 edges/iter, software-pipelined ----
// CSR entry fetched via UNIFORM global load per half-wave (no DS broadcast);
// se is prefetched 2 iters ahead, k/v/ea data 1 iter ahead.
// lane: gslot = lane>>5 (edge slot), j = lane&31 (cols j*4..+4, head j>>3)
__global__ __launch_bounds__(256) void k_conv(
        const float* __restrict__ q, const float* __restrict__ k,
        const float* __restrict__ v, const float* __restrict__ ea,
        const float* __restrict__ We,
        const int* __restrict__ rowptr, const int2* __restrict__ ecsr,
        const int* __restrict__ batch,
        float* __restrict__ hout, float* __restrict__ gsum, int mode) {
    const int wid = (blockIdx.x * blockDim.x + threadIdx.x) >> 6;
    if (wid >= NN) return;
    const int lane = threadIdx.x & 63;
    const int gslot = lane >> 5;
    const int j = lane & 31;
    const int c0 = j * 4;
    float4 we[ED];
    #pragma unroll
    for (int jj = 0; jj < ED; ++jj)
        we[jj] = *(const float4*)&We[jj * HC + c0];
    const int beg = rowptr[wid];
    const int end = rowptr[wid + 1];
    const float4 qq = *(const float4*)&q[(size_t)wid * HC + c0];
    float den = 0.f, ax = 0.f, ay = 0.f, az = 0.f, aw = 0.f;

    const int deg = end - beg;
    if (deg > 0) {
        const int niter = (deg + 1) >> 1;
        const int last = end - 1;
        // pipeline prologue
        int2 se_cur = ecsr[min(beg + gslot, last)];
        int2 se_nxt = ecsr[min(beg + 2 + gslot, last)];
        const float4* e4 = (const float4*)&ea[(size_t)se_cur.y * ED];
        float4 A0 = e4[0], A1 = e4[1], A2 = e4[2], A3 = e4[3];
        float4 kk4 = *(const float4*)&k[(size_t)se_cur.x * HC + c0];
        float4 vv4 = *(const float4*)&v[(size_t)se_cur.x * HC + c0];
        bool act = (beg + gslot) < end;

        for (int i = 0; i < niter; ++i) {
            // prefetch se for i+2 (no deps)
            int2 se_fut = ecsr[min(beg + 2 * (i + 2) + gslot, last)];
            // issue data loads for i+1 (se_nxt loaded one iter ago)
            const float4* en4 = (const float4*)&ea[(size_t)se_nxt.y * ED];
            float4 An0 = en4[0], An1 = en4[1], An2 = en4[2], An3 = en4[3];
            float4 kkn = *(const float4*)&k[(size_t)se_nxt.x * HC + c0];
            float4 vvn = *(const float4*)&v[(size_t)se_nxt.x * HC + c0];
            bool actn = (beg + 2 * (i + 1) + gslot) < end;
            // compute current iteration
            float ar[ED] = {A0.x, A0.y, A0.z, A0.w, A1.x, A1.y, A1.z, A1.w,
                            A2.x, A2.y, A2.z, A2.w, A3.x, A3.y, A3.z, A3.w};
            float4 e = make_float4(0.f, 0.f, 0.f, 0.f);
            #pragma unroll
            for (int jj = 0; jj < ED; ++jj) {
                e.x += ar[jj] * we[jj].x; e.y += ar[jj] * we[jj].y;
                e.z += ar[jj] * we[jj].z; e.w += ar[jj] * we[jj].w;
            }
            float part = qq.x * (kk4.x + e.x) + qq.y * (kk4.y + e.y)
                       + qq.z * (kk4.z + e.z) + qq.w * (kk4.w + e.w);
            part += __shfl_xor(part, 1);
            part += __shfl_xor(part, 2);
            part += __shfl_xor(part, 4);   // per-head logit (8 lanes/head)
            float p = act ? __expf(part * 0.17677669529663687f) : 0.f;
            den += p;
            ax += p * (vv4.x + e.x);
            ay += p * (vv4.y + e.y);
            az += p * (vv4.z + e.z);
            aw += p * (vv4.w + e.w);
            // rotate pipeline registers
            A0 = An0; A1 = An1; A2 = An2; A3 = An3;
            kk4 = kkn; vv4 = vvn;
            se_nxt = se_fut;
            act = actn;
        }
    }
    // merge the two edge-slot partials
    den += __shfl_xor(den, 32);
    ax += __shfl_xor(ax, 32); ay += __shfl_xor(ay, 32);
    az += __shfl_xor(az, 32); aw += __shfl_xor(aw, 32);
    float inv = 1.f / (den + 1e-16f);
    float4 o = make_float4(ax * inv, ay * inv, az * inv, aw * inv);

    const int b = batch[wid];
    if (mode == 0) {
        o.x = fmaxf(o.x, 0.f); o.y = fmaxf(o.y, 0.f);
        o.z = fmaxf(o.z, 0.f); o.w = fmaxf(o.w, 0.f);
        if (gslot == 0) *(float4*)&hout[(size_t)wid * HC + c0] = o;
    }
    // head-sum: xor 8 and 16 fold the 4 heads (j>>3) keeping j&7
    float sx = o.x, sy = o.y, sz = o.z, sw = o.w;
    sx += __shfl_xor(sx, 8);  sy += __shfl_xor(sy, 8);
    sz += __shfl_xor(sz, 8);  sw += __shfl_xor(sw, 8);
    sx += __shfl_xor(sx, 16); sy += __shfl_xor(sy, 16);
    sz += __shfl_xor(sz, 16); sw += __shfl_xor(sw, 16);
    if (lane < 8) {
        float px, py, pz, pw;
        if (mode == 0) {
            px = 0.25f * sx; py = 0.25f * sy; pz = 0.25f * sz; pw = 0.25f * sw;
        } else {
            px = fmaxf(0.25f * sx, 0.f); py = fmaxf(0.25f * sy, 0.f);
            pz = fmaxf(0.25f * sz, 0.f); pw = fmaxf(0.25f * sw, 0.f);
        }
        atomicAdd(&gsum[b * CD + lane * 4 + 0], px);
        atomicAdd(&gsum[b * CD + lane * 4 + 1], py);
        atomicAdd(&gsum[b * CD + lane * 4 + 2], pz);
        atomicAdd(&gsum[b * CD + lane * 4 + 3], pw);
    }
}

// ---- final MLP + log_softmax: one block per graph ----
__global__ __launch_bounds__(128) void k_final(
        const float* __restrict__ gsum, const float* __restrict__ cnt,
        const float* __restrict__ W1, const float* __restrict__ b1,
        const float* __restrict__ W2, const float* __restrict__ b2,
        float* __restrict__ out) {
    __shared__ float G[96];
    __shared__ float Y[96];
    __shared__ float Z[10];
    const int g = blockIdx.x;
    const int t = threadIdx.x;
    const float cn = fmaxf(cnt[g], 1.f);
    if (t < 96) {
        int layer = t / 32, c = t % 32;
        G[t] = gsum[layer * NG * CD + g * CD + c] / cn;
    }
    __syncthreads();
    if (t < 96) {
        float s = b1[t];
        #pragma unroll 4
        for (int d = 0; d < 96; ++d) s += G[d] * W1[d * 96 + t];
        Y[t] = fmaxf(s, 0.f);
    }
    __syncthreads();
    if (t < 10) {
        float s = b2[t];
        #pragma unroll 4
        for (int d = 0; d < 96; ++d) s += Y[d] * W2[d * 10 + t];
        Z[t] = s;
    }
    __syncthreads();
    if (t < 10) {
        float mx = Z[0];
        #pragma unroll
        for (int o = 1; o < 10; ++o) mx = fmaxf(mx, Z[o]);
        float se = 0.f;
        #pragma unroll
        for (int o = 0; o < 10; ++o) se += expf(Z[o] - mx);
        out[g * 10 + t] = Z[t] - (mx + logf(se));
    }
}

extern "C" void kernel_launch(void* const* d_in, const int* in_sizes, int n_in,
                              void* d_out, int out_size, void* d_ws, size_t ws_size,
                              hipStream_t stream) {
    const float* x        = (const float*)d_in[0];
    const float* ea       = (const float*)d_in[1];
    const int*   ei       = (const int*)d_in[2];
    const int*   batch    = (const int*)d_in[3];
    const float* Wq[3] = {(const float*)d_in[4],  (const float*)d_in[8],  (const float*)d_in[12]};
    const float* Wk[3] = {(const float*)d_in[5],  (const float*)d_in[9],  (const float*)d_in[13]};
    const float* Wv[3] = {(const float*)d_in[6],  (const float*)d_in[10], (const float*)d_in[14]};
    const float* We[3] = {(const float*)d_in[7],  (const float*)d_in[11], (const float*)d_in[15]};
    const float* W1 = (const float*)d_in[16];
    const float* b1 = (const float*)d_in[17];
    const float* W2 = (const float*)d_in[18];
    const float* b2 = (const float*)d_in[19];
    float* out = (float*)d_out;

    // workspace layout
    float* ws = (float*)d_ws;
    float* q    = ws;                     // NN*HC
    float* kbuf = q + (size_t)NN * HC;    // NN*HC
    float* vbuf = kbuf + (size_t)NN * HC; // NN*HC
    float* h1   = vbuf + (size_t)NN * HC; // NN*HC
    float* h2   = h1 + (size_t)NN * HC;   // NN*HC
    float* gsum = h2 + (size_t)NN * HC;   // 3*NG*CD
    float* cnt  = gsum + 3 * NG * CD;     // NG
    int* deg    = (int*)(cnt + NG);       // NN
    int* rowptr = deg + NN;               // NN+2 (pad keeps int2 8B-aligned)
    int* nextp  = rowptr + NN + 2;        // NN
    int2* ecsr  = (int2*)(nextp + NN);    // NE

    hipMemsetAsync(gsum, 0, (3 * NG * CD + NG) * sizeof(float), stream);
    hipMemsetAsync(deg, 0, NN * sizeof(int), stream);

    // CSR build (edge_index shared by all layers)
    k_hist<<<(NE + 255) / 256, 256, 0, stream>>>(ei, deg);
    k_scan<<<1, 1024, 0, stream>>>(deg, rowptr, nextp);
    k_scatter<<<(NE + 255) / 256, 256, 0, stream>>>(ei, nextp, ecsr);
    k_count<<<(NN + 255) / 256, 256, 0, stream>>>(batch, cnt);

    const float* conv_in[3] = {x, h1, h2};
    float* conv_out[3] = {h1, h2, nullptr};
    const int CONV_BLOCKS = (NN * 64) / 256;   // one wave per node

    for (int l = 0; l < 3; ++l) {
        k_qkv<<<dim3(NN / 32, 3), 256, 0, stream>>>(conv_in[l], Wq[l], Wk[l], Wv[l], q, kbuf, vbuf);
        k_conv<<<CONV_BLOCKS, 256, 0, stream>>>(q, kbuf, vbuf, ea, We[l],
                rowptr, ecsr, batch,
                conv_out[l], gsum + l * NG * CD, (l < 2) ? 0 : 1);
    }
    k_final<<<NG, 128, 0, stream>>>(gsum, cnt, W1, b1, W2, b2, out);
}